// Round 15
// baseline (458.093 us; speedup 1.0000x reference)
//
#include <hip/hip_runtime.h>
#include <hip/hip_bf16.h>
#include <cstdint>

#define D_MODEL 4096
#define NFIB    64
#define NBATCH  4
#define LSEQ    4096
#define NTOK    (NBATCH * LSEQ)   // 16384
#define NSL     8                 // K slices in p1

typedef __attribute__((ext_vector_type(4))) float f32x4;
typedef __attribute__((ext_vector_type(8))) short bf16x8;

__device__ __forceinline__ unsigned short f2bf(float f) {
  unsigned int u = __builtin_bit_cast(unsigned int, f);
  u += 0x7FFFu + ((u >> 16) & 1u);
  return (unsigned short)(u >> 16);
}

__device__ __forceinline__ bf16x8 cvt8(f32x4 a, f32x4 b) {
  union { __hip_bfloat162 h2[4]; bf16x8 v; } u;
  u.h2[0] = __float22bfloat162_rn(make_float2(a[0], a[1]));
  u.h2[1] = __float22bfloat162_rn(make_float2(a[2], a[3]));
  u.h2[2] = __float22bfloat162_rn(make_float2(b[0], b[1]));
  u.h2[3] = __float22bfloat162_rn(make_float2(b[2], b[3]));
  return u.v;
}

__device__ __forceinline__ void addbf8(f32x4& x0, f32x4& x1, bf16x8 v) {
#pragma unroll
  for (int j = 0; j < 4; ++j)
    x0[j] += __builtin_bit_cast(float, (uint32_t)(unsigned short)v[j] << 16);
#pragma unroll
  for (int j = 0; j < 4; ++j)
    x1[j] += __builtin_bit_cast(float, (uint32_t)(unsigned short)v[j + 4] << 16);
}

// ---------------------------------------------------------------------------
// DIAGNOSTIC: m13-style pure grid-stride copy. Read H (256 MB), write two
// 256 MB ws regions. 768 MB total traffic, no compute, no reuse. This is
// the canonical 6.3 TB/s pattern; its measured hbm_gbps is ground truth
// for this container's achievable mixed read+write bandwidth.
// ---------------------------------------------------------------------------
__global__ __launch_bounds__(256, 8) void diag_copy(const f32x4* __restrict__ in,
                                                    f32x4* __restrict__ outA,
                                                    f32x4* __restrict__ outB) {
  const int stride = 2048 * 256;
  int i = blockIdx.x * 256 + threadIdx.x;
#pragma unroll 4
  for (; i < NTOK * (D_MODEL / 4); i += stride) {
    f32x4 v = in[i];
    outA[i] = v;
    outB[i] = v;
  }
}

// ---------------------------------------------------------------------------
// Blocks 0..3: S_b = Q_b - I = 2(I-A)^{-1}A (Gauss-Jordan, 2 barriers/pivot).
// Blocks 4..1027: W_down -> bf16 wave-swizzled Wd2.
// ---------------------------------------------------------------------------
__global__ __launch_bounds__(256) void prep1_kernel(const float* __restrict__ A,
                                                    const float* __restrict__ Wd,
                                                    float* __restrict__ S,
                                                    unsigned short* __restrict__ Wd2) {
  const int blk = blockIdx.x;
  if (blk >= NBATCH) {
    int idx = (blk - NBATCH) * 256 + threadIdx.x;
    int j    = idx & 7;
    int lane = (idx >> 3) & 63;
    int nf   = (idx >> 9) & 3;
    int ks   = idx >> 11;
    int row = nf * 16 + (lane & 15);
    int col = ks * 32 + (lane >> 4) * 8 + j;
    Wd2[idx] = f2bf(Wd[row * D_MODEL + col]);
    return;
  }
  __shared__ float M[64][66];
  __shared__ float R[64][66];
  const int b = blk;
  const int tid = threadIdx.x;
  const int k = tid & 63;
  const int g = tid >> 6;
  const float* Ab = A + b * 4096;
#pragma unroll
  for (int ii = 0; ii < 16; ++ii) {
    int i = g * 16 + ii;
    float a = Ab[i * 64 + k];
    M[i][k] = ((i == k) ? 1.0f : 0.0f) - a;
    R[i][k] = 2.0f * a;
  }
  for (int j = 0; j < 64; ++j) {
    __syncthreads();
    float pr  = 1.0f / M[j][j];
    float mjk = M[j][k], rjk = R[j][k];
    float f[16];
#pragma unroll
    for (int ii = 0; ii < 16; ++ii) f[ii] = M[g * 16 + ii][j] * pr;
    __syncthreads();
#pragma unroll
    for (int ii = 0; ii < 16; ++ii) {
      int i = g * 16 + ii;
      if (i != j) { M[i][k] -= f[ii] * mjk; R[i][k] -= f[ii] * rjk; }
    }
  }
  __syncthreads();
  float* Sb = S + b * 4096;
#pragma unroll
  for (int ii = 0; ii < 16; ++ii) {
    int i = g * 16 + ii;
    Sb[i * 64 + k] = R[i][k] / M[i][i];
  }
}

// ---------------------------------------------------------------------------
// U2[(((b*256+nt)*64+lane)*2+h)*8+j] = bf16(alpha*(Wup@S)[d][f]),
//   d = nt*16+(lane&15), f = h*32+(lane>>4)*8+j.
// ---------------------------------------------------------------------------
__global__ __launch_bounds__(256) void prep_u_kernel(const float* __restrict__ Wup,
                                                     const float* __restrict__ S,
                                                     const float* __restrict__ alpha_p,
                                                     unsigned short* __restrict__ U2) {
  __shared__ float Sl[4096];
  const int blk = blockIdx.x;          // 0..511
  const int b = blk >> 7;
  const int ntg = blk & 127;           // 2 nt per block
  const float* Sb = S + b * 4096;
  for (int i = threadIdx.x; i < 1024; i += 256)
    ((f32x4*)Sl)[i] = ((const f32x4*)Sb)[i];
  __syncthreads();

  const int t = threadIdx.x;
  const int nt   = ntg * 2 + (t >> 7);
  const int h    = (t >> 6) & 1;
  const int lane = t & 63;
  const int d = nt * 16 + (lane & 15);
  const int fbase = h * 32 + (lane >> 4) * 8;
  const float alpha = alpha_p[0];
  const f32x4* wr = (const f32x4*)(Wup + d * 64);

  float s[8];
#pragma unroll
  for (int j = 0; j < 8; ++j) s[j] = 0.f;
#pragma unroll
  for (int g4 = 0; g4 < 16; ++g4) {
    f32x4 wv = wr[g4];
#pragma unroll
    for (int gg = 0; gg < 4; ++gg) {
      const float* srow = &Sl[(g4 * 4 + gg) * 64 + fbase];
      float wvg = wv[gg];
#pragma unroll
      for (int j = 0; j < 8; ++j) s[j] += wvg * srow[j];
    }
  }
  bf16x8 v;
#pragma unroll
  for (int j = 0; j < 8; ++j) v[j] = (short)f2bf(alpha * s[j]);
  *(bf16x8*)(U2 + ((((size_t)b * 256 + nt) * 64 + lane) * 2 + h) * 8) = v;
}

// ---------------------------------------------------------------------------
// P1: partial F slices. 256 token-groups(64) x 8 slices = 2048 blocks.
// Wave w = token tile (tg*64 + w*16 rows), all 64 fibers, K-slice ks
// (512 cols = 16 steps). Hot loop per step: 2 H loads + 4 Wd2 (L2) + 4 MFMA.
// ---------------------------------------------------------------------------
__global__ __launch_bounds__(256, 4) void p1_kernel(
    const float* __restrict__ H, const unsigned short* __restrict__ Wd2,
    unsigned short* __restrict__ Fpb) {
  const int blk = blockIdx.x;
  const int tg = blk >> 3;          // 0..255 : 64-token group
  const int ks = blk & 7;           // 0..7   : 512-col K slice
  const int tid = threadIdx.x;
  const int w = tid >> 6, l = tid & 63, lr = l & 15, lq = l >> 4;

  const int rowW = tg * 64 + w * 16;              // wave's 16 tokens
  const float* ha = H + (size_t)(rowW + lr) * D_MODEL + ks * 512 + lq * 8;
  const unsigned short* wb = Wd2 + (((size_t)(ks * 16) * 4) * 64 + l) * 8;

  f32x4 acc[4];
#pragma unroll
  for (int nf = 0; nf < 4; ++nf) acc[nf] = (f32x4){0, 0, 0, 0};

  for (int s = 0; s < 16; ++s) {
    const float* hp = ha + s * 32;
    f32x4 a0 = *(const f32x4*)hp;
    f32x4 a1 = *(const f32x4*)(hp + 4);
    bf16x8 afr = cvt8(a0, a1);
    const unsigned short* wp = wb + (size_t)s * 2048;
#pragma unroll
    for (int nf = 0; nf < 4; ++nf) {
      bf16x8 bfr = *(const bf16x8*)(wp + (size_t)nf * 512);
      acc[nf] = __builtin_amdgcn_mfma_f32_16x16x32_bf16(afr, bfr, acc[nf], 0, 0, 0);
    }
  }

  unsigned short* fp = Fpb + (size_t)ks * (NTOK * 64);
#pragma unroll
  for (int nf = 0; nf < 4; ++nf)
#pragma unroll
    for (int rr = 0; rr < 4; ++rr)
      fp[(size_t)(rowW + lq * 4 + rr) * 64 + nf * 16 + lr] = f2bf(acc[nf][rr]);
}

// ---------------------------------------------------------------------------
// PF: F2[t][f] = bf16( sum_ks Fpb[ks][t][f] ).  512 blocks, 8 bf16/thread.
// ---------------------------------------------------------------------------
__global__ __launch_bounds__(256, 8) void pf_kernel(
    const unsigned short* __restrict__ Fpb, unsigned short* __restrict__ F2) {
  const int idx = blockIdx.x * 256 + threadIdx.x;
  const size_t off = (size_t)idx * 8;
  f32x4 x0 = {0, 0, 0, 0}, x1 = {0, 0, 0, 0};
#pragma unroll
  for (int ks = 0; ks < NSL; ++ks)
    addbf8(x0, x1, *(const bf16x8*)(Fpb + (size_t)ks * (NTOK * 64) + off));
  *(bf16x8*)(F2 + off) = cvt8(x0, x1);
}

// ---------------------------------------------------------------------------
// P2: Out = H + F @ U^T.  Grid 4096 = 256 token-groups(64) x 16 col-chunks.
// U (32 VGPR) + F (32 VGPR) preloaded; main loop = 16 x {1 HBM residual
// load, 2 MFMA, 1 store}.
// ---------------------------------------------------------------------------
__global__ __launch_bounds__(256, 4) void p2_kernel(
    const float* __restrict__ H, const unsigned short* __restrict__ F2,
    const unsigned short* __restrict__ U2, float* __restrict__ Out) {
  const int blk = blockIdx.x;
  const int tg = blk >> 4;          // 0..255 : 64-token group
  const int cc = blk & 15;          // 0..15  : 256-col chunk
  const int rowB = tg * 64;
  const int b = rowB >> 12;
  const int tid = threadIdx.x;
  const int w = tid >> 6, l = tid & 63, lr = l & 15, lq = l >> 4;

  const int colW = cc * 256 + w * 64;
  const int nt0 = colW >> 4;

  const unsigned short* ub = U2 + (((size_t)b * 256 + nt0) * 64 + l) * 16;
  bf16x8 u0[4], u1[4];
#pragma unroll
  for (int nt = 0; nt < 4; ++nt) {
    u0[nt] = *(const bf16x8*)(ub + (size_t)nt * 1024);
    u1[nt] = *(const bf16x8*)(ub + (size_t)nt * 1024 + 8);
  }

  bf16x8 fb0[4], fb1[4];
#pragma unroll
  for (int g = 0; g < 4; ++g) {
    const unsigned short* fp = F2 + (size_t)(rowB + g * 16 + lr) * 64 + lq * 8;
    fb0[g] = *(const bf16x8*)fp;
    fb1[g] = *(const bf16x8*)(fp + 32);
  }

#pragma unroll
  for (int g = 0; g < 4; ++g) {
    const size_t rbase = (size_t)(rowB + g * 16 + lr) * D_MODEL + colW + lq * 4;
#pragma unroll
    for (int nt = 0; nt < 4; ++nt) {
      f32x4 hr = *(const f32x4*)(H + rbase + nt * 16);
      f32x4 c = {0, 0, 0, 0};
      c = __builtin_amdgcn_mfma_f32_16x16x32_bf16(u0[nt], fb0[g], c, 0, 0, 0);
      c = __builtin_amdgcn_mfma_f32_16x16x32_bf16(u1[nt], fb1[g], c, 0, 0, 0);
      *(f32x4*)(Out + rbase + nt * 16) = hr + c;
    }
  }
}

// ---------------------------------------------------------------------------
extern "C" void kernel_launch(void* const* d_in, const int* in_sizes, int n_in,
                              void* d_out, int out_size, void* d_ws, size_t ws_size,
                              hipStream_t stream) {
  const float* h_t    = (const float*)d_in[0];
  // d_in[1] = z0 (unused by the reference)
  const float* A_u    = (const float*)d_in[2];
  const float* alpha  = (const float*)d_in[3];
  const float* W_down = (const float*)d_in[4];
  const float* W_up   = (const float*)d_in[5];
  float* out = (float*)d_out;

  char* ws = (char*)d_ws;
  float*          S   = (float*)ws;                               // 64 KiB
  unsigned short* Wd2 = (unsigned short*)(ws + (64 << 10));       // 512 KiB
  unsigned short* U2  = (unsigned short*)(ws + (576 << 10));      // 2 MiB
  unsigned short* Fpb = (unsigned short*)(ws + (2624 << 10));     // 16 MiB
  unsigned short* F2  = (unsigned short*)(ws + (19008 << 10));    // 2 MiB
  f32x4* cpA = (f32x4*)(ws + ((size_t)160 << 20));                // 256 MiB scratch
  f32x4* cpB = (f32x4*)(ws + ((size_t)480 << 20));                // 256 MiB scratch

  prep1_kernel<<<NBATCH + 1024, 256, 0, stream>>>(A_u, W_down, S, Wd2);
  prep_u_kernel<<<512, 256, 0, stream>>>(W_up, S, alpha, U2);
  diag_copy<<<2048, 256, 0, stream>>>((const f32x4*)h_t, cpA, cpB);
  p1_kernel<<<2048, 256, 0, stream>>>(h_t, Wd2, Fpb);
  pf_kernel<<<512, 256, 0, stream>>>(Fpb, F2);
  p2_kernel<<<4096, 256, 0, stream>>>(h_t, F2, U2, out);
}

// Round 16
// 267.476 us; speedup vs baseline: 1.7127x; 1.7127x over previous
//
#include <hip/hip_runtime.h>
#include <hip/hip_bf16.h>
#include <cstdint>

#define D_MODEL 4096
#define NFIB    64
#define NBATCH  4
#define LSEQ    4096
#define NTOK    (NBATCH * LSEQ)   // 16384
#define NSL     8                 // K slices in p1

typedef __attribute__((ext_vector_type(4))) float f32x4;
typedef __attribute__((ext_vector_type(8))) short bf16x8;

__device__ __forceinline__ unsigned short f2bf(float f) {
  unsigned int u = __builtin_bit_cast(unsigned int, f);
  u += 0x7FFFu + ((u >> 16) & 1u);
  return (unsigned short)(u >> 16);
}

__device__ __forceinline__ bf16x8 cvt8(f32x4 a, f32x4 b) {
  union { __hip_bfloat162 h2[4]; bf16x8 v; } u;
  u.h2[0] = __float22bfloat162_rn(make_float2(a[0], a[1]));
  u.h2[1] = __float22bfloat162_rn(make_float2(a[2], a[3]));
  u.h2[2] = __float22bfloat162_rn(make_float2(b[0], b[1]));
  u.h2[3] = __float22bfloat162_rn(make_float2(b[2], b[3]));
  return u.v;
}

__device__ __forceinline__ void addbf8(f32x4& x0, f32x4& x1, bf16x8 v) {
#pragma unroll
  for (int j = 0; j < 4; ++j)
    x0[j] += __builtin_bit_cast(float, (uint32_t)(unsigned short)v[j] << 16);
#pragma unroll
  for (int j = 0; j < 4; ++j)
    x1[j] += __builtin_bit_cast(float, (uint32_t)(unsigned short)v[j + 4] << 16);
}

// ---------------------------------------------------------------------------
// Blocks 0..3: S_b = Q_b - I = 2(I-A)^{-1}A (Gauss-Jordan, 2 barriers/pivot).
// Blocks 4..1027: W_down -> bf16 wave-swizzled Wd2.
// ---------------------------------------------------------------------------
__global__ __launch_bounds__(256) void prep1_kernel(const float* __restrict__ A,
                                                    const float* __restrict__ Wd,
                                                    float* __restrict__ S,
                                                    unsigned short* __restrict__ Wd2) {
  const int blk = blockIdx.x;
  if (blk >= NBATCH) {
    int idx = (blk - NBATCH) * 256 + threadIdx.x;
    int j    = idx & 7;
    int lane = (idx >> 3) & 63;
    int nf   = (idx >> 9) & 3;
    int ks   = idx >> 11;
    int row = nf * 16 + (lane & 15);
    int col = ks * 32 + (lane >> 4) * 8 + j;
    Wd2[idx] = f2bf(Wd[row * D_MODEL + col]);
    return;
  }
  __shared__ float M[64][66];
  __shared__ float R[64][66];
  const int b = blk;
  const int tid = threadIdx.x;
  const int k = tid & 63;
  const int g = tid >> 6;
  const float* Ab = A + b * 4096;
#pragma unroll
  for (int ii = 0; ii < 16; ++ii) {
    int i = g * 16 + ii;
    float a = Ab[i * 64 + k];
    M[i][k] = ((i == k) ? 1.0f : 0.0f) - a;
    R[i][k] = 2.0f * a;
  }
  for (int j = 0; j < 64; ++j) {
    __syncthreads();
    float pr  = 1.0f / M[j][j];
    float mjk = M[j][k], rjk = R[j][k];
    float f[16];
#pragma unroll
    for (int ii = 0; ii < 16; ++ii) f[ii] = M[g * 16 + ii][j] * pr;
    __syncthreads();
#pragma unroll
    for (int ii = 0; ii < 16; ++ii) {
      int i = g * 16 + ii;
      if (i != j) { M[i][k] -= f[ii] * mjk; R[i][k] -= f[ii] * rjk; }
    }
  }
  __syncthreads();
  float* Sb = S + b * 4096;
#pragma unroll
  for (int ii = 0; ii < 16; ++ii) {
    int i = g * 16 + ii;
    Sb[i * 64 + k] = R[i][k] / M[i][i];
  }
}

// ---------------------------------------------------------------------------
// U2[(((b*256+nt)*64+lane)*2+h)*8+j] = bf16(alpha*(Wup@S)[d][f]),
//   d = nt*16+(lane&15), f = h*32+(lane>>4)*8+j.
// ---------------------------------------------------------------------------
__global__ __launch_bounds__(256) void prep_u_kernel(const float* __restrict__ Wup,
                                                     const float* __restrict__ S,
                                                     const float* __restrict__ alpha_p,
                                                     unsigned short* __restrict__ U2) {
  __shared__ float Sl[4096];
  const int blk = blockIdx.x;          // 0..511
  const int b = blk >> 7;
  const int ntg = blk & 127;           // 2 nt per block
  const float* Sb = S + b * 4096;
  for (int i = threadIdx.x; i < 1024; i += 256)
    ((f32x4*)Sl)[i] = ((const f32x4*)Sb)[i];
  __syncthreads();

  const int t = threadIdx.x;
  const int nt   = ntg * 2 + (t >> 7);
  const int h    = (t >> 6) & 1;
  const int lane = t & 63;
  const int d = nt * 16 + (lane & 15);
  const int fbase = h * 32 + (lane >> 4) * 8;
  const float alpha = alpha_p[0];
  const f32x4* wr = (const f32x4*)(Wup + d * 64);

  float s[8];
#pragma unroll
  for (int j = 0; j < 8; ++j) s[j] = 0.f;
#pragma unroll
  for (int g4 = 0; g4 < 16; ++g4) {
    f32x4 wv = wr[g4];
#pragma unroll
    for (int gg = 0; gg < 4; ++gg) {
      const float* srow = &Sl[(g4 * 4 + gg) * 64 + fbase];
      float wvg = wv[gg];
#pragma unroll
      for (int j = 0; j < 8; ++j) s[j] += wvg * srow[j];
    }
  }
  bf16x8 v;
#pragma unroll
  for (int j = 0; j < 8; ++j) v[j] = (short)f2bf(alpha * s[j]);
  *(bf16x8*)(U2 + ((((size_t)b * 256 + nt) * 64 + lane) * 2 + h) * 8) = v;
}

// ---------------------------------------------------------------------------
// P1: partial F slices. 256 token-groups(64) x 8 slices = 2048 blocks,
// ASCENDING token order (leaves H tail L3-hot for p2's descending start;
// previous replay's p2 leaves H head L3-hot for this kernel's start).
// Wave w = token tile, all 64 fibers, K-slice ks (512 cols = 16 steps).
// ---------------------------------------------------------------------------
__global__ __launch_bounds__(256, 4) void p1_kernel(
    const float* __restrict__ H, const unsigned short* __restrict__ Wd2,
    unsigned short* __restrict__ Fpb) {
  const int blk = blockIdx.x;
  const int tg = blk >> 3;          // 0..255 : 64-token group (ascending)
  const int ks = blk & 7;           // 0..7   : 512-col K slice
  const int tid = threadIdx.x;
  const int w = tid >> 6, l = tid & 63, lr = l & 15, lq = l >> 4;

  const int rowW = tg * 64 + w * 16;              // wave's 16 tokens
  const float* ha = H + (size_t)(rowW + lr) * D_MODEL + ks * 512 + lq * 8;
  const unsigned short* wb = Wd2 + (((size_t)(ks * 16) * 4) * 64 + l) * 8;

  f32x4 acc[4];
#pragma unroll
  for (int nf = 0; nf < 4; ++nf) acc[nf] = (f32x4){0, 0, 0, 0};

  for (int s = 0; s < 16; ++s) {
    const float* hp = ha + s * 32;
    f32x4 a0 = *(const f32x4*)hp;
    f32x4 a1 = *(const f32x4*)(hp + 4);
    bf16x8 afr = cvt8(a0, a1);
    const unsigned short* wp = wb + (size_t)s * 2048;
#pragma unroll
    for (int nf = 0; nf < 4; ++nf) {
      bf16x8 bfr = *(const bf16x8*)(wp + (size_t)nf * 512);
      acc[nf] = __builtin_amdgcn_mfma_f32_16x16x32_bf16(afr, bfr, acc[nf], 0, 0, 0);
    }
  }

  unsigned short* fp = Fpb + (size_t)ks * (NTOK * 64);
#pragma unroll
  for (int nf = 0; nf < 4; ++nf)
#pragma unroll
    for (int rr = 0; rr < 4; ++rr)
      fp[(size_t)(rowW + lq * 4 + rr) * 64 + nf * 16 + lr] = f2bf(acc[nf][rr]);
}

// ---------------------------------------------------------------------------
// PF: F2[t][f] = bf16( sum_ks Fpb[ks][t][f] ).  512 blocks, 8 bf16/thread.
// ---------------------------------------------------------------------------
__global__ __launch_bounds__(256, 8) void pf_kernel(
    const unsigned short* __restrict__ Fpb, unsigned short* __restrict__ F2) {
  const int idx = blockIdx.x * 256 + threadIdx.x;
  const size_t off = (size_t)idx * 8;
  f32x4 x0 = {0, 0, 0, 0}, x1 = {0, 0, 0, 0};
#pragma unroll
  for (int ks = 0; ks < NSL; ++ks)
    addbf8(x0, x1, *(const bf16x8*)(Fpb + (size_t)ks * (NTOK * 64) + off));
  *(bf16x8*)(F2 + off) = cvt8(x0, x1);
}

// ---------------------------------------------------------------------------
// P2: Out = H + F @ U^T.  Grid 4096 = 256 token-groups(64) x 16 col-chunks,
// token groups processed in DESCENDING order: p1 just finished reading H's
// tail, so p2's first reads are L3 hits; p2 ends at H's head, priming the
// next replay's p1. U (32 VGPR) + F (32 VGPR) preloaded; main loop =
// 16 x {1 HBM residual load, 2 MFMA, 1 store}.
// ---------------------------------------------------------------------------
__global__ __launch_bounds__(256, 4) void p2_kernel(
    const float* __restrict__ H, const unsigned short* __restrict__ F2,
    const unsigned short* __restrict__ U2, float* __restrict__ Out) {
  const int blk = blockIdx.x;
  const int tg = 255 - (blk >> 4);  // DESCENDING token groups
  const int cc = blk & 15;          // 0..15  : 256-col chunk
  const int rowB = tg * 64;
  const int b = rowB >> 12;
  const int tid = threadIdx.x;
  const int w = tid >> 6, l = tid & 63, lr = l & 15, lq = l >> 4;

  const int colW = cc * 256 + w * 64;
  const int nt0 = colW >> 4;

  const unsigned short* ub = U2 + (((size_t)b * 256 + nt0) * 64 + l) * 16;
  bf16x8 u0[4], u1[4];
#pragma unroll
  for (int nt = 0; nt < 4; ++nt) {
    u0[nt] = *(const bf16x8*)(ub + (size_t)nt * 1024);
    u1[nt] = *(const bf16x8*)(ub + (size_t)nt * 1024 + 8);
  }

  bf16x8 fb0[4], fb1[4];
#pragma unroll
  for (int g = 0; g < 4; ++g) {
    const unsigned short* fp = F2 + (size_t)(rowB + g * 16 + lr) * 64 + lq * 8;
    fb0[g] = *(const bf16x8*)fp;
    fb1[g] = *(const bf16x8*)(fp + 32);
  }

#pragma unroll
  for (int g = 0; g < 4; ++g) {
    const size_t rbase = (size_t)(rowB + g * 16 + lr) * D_MODEL + colW + lq * 4;
#pragma unroll
    for (int nt = 0; nt < 4; ++nt) {
      f32x4 hr = *(const f32x4*)(H + rbase + nt * 16);
      f32x4 c = {0, 0, 0, 0};
      c = __builtin_amdgcn_mfma_f32_16x16x32_bf16(u0[nt], fb0[g], c, 0, 0, 0);
      c = __builtin_amdgcn_mfma_f32_16x16x32_bf16(u1[nt], fb1[g], c, 0, 0, 0);
      *(f32x4*)(Out + rbase + nt * 16) = hr + c;
    }
  }
}

// ---------------------------------------------------------------------------
extern "C" void kernel_launch(void* const* d_in, const int* in_sizes, int n_in,
                              void* d_out, int out_size, void* d_ws, size_t ws_size,
                              hipStream_t stream) {
  const float* h_t    = (const float*)d_in[0];
  // d_in[1] = z0 (unused by the reference)
  const float* A_u    = (const float*)d_in[2];
  const float* alpha  = (const float*)d_in[3];
  const float* W_down = (const float*)d_in[4];
  const float* W_up   = (const float*)d_in[5];
  float* out = (float*)d_out;

  char* ws = (char*)d_ws;
  float*          S   = (float*)ws;                               // 64 KiB
  unsigned short* Wd2 = (unsigned short*)(ws + (64 << 10));       // 512 KiB
  unsigned short* U2  = (unsigned short*)(ws + (576 << 10));      // 2 MiB
  unsigned short* Fpb = (unsigned short*)(ws + (2624 << 10));     // 16 MiB
  unsigned short* F2  = (unsigned short*)(ws + (19008 << 10));    // 2 MiB

  prep1_kernel<<<NBATCH + 1024, 256, 0, stream>>>(A_u, W_down, S, Wd2);
  prep_u_kernel<<<512, 256, 0, stream>>>(W_up, S, alpha, U2);
  p1_kernel<<<2048, 256, 0, stream>>>(h_t, Wd2, Fpb);
  pf_kernel<<<512, 256, 0, stream>>>(Fpb, F2);
  p2_kernel<<<4096, 256, 0, stream>>>(h_t, F2, U2, out);
}